// Round 2
// baseline (7151.595 us; speedup 1.0000x reference)
//
#include <hip/hip_runtime.h>
#include <cstdint>
#include <cstddef>

typedef unsigned int UINT;
typedef unsigned short USHORT;

// ---------- constants ----------
// B=32 S=128 V=32000 NT=64 NE=100 H=400 NL=128 NM=100
#define TOKENS 4096      // B*S
#define HID 400
#define G4 1600          // 4*H
#define SEQ 128
#define NB 32
#define NPOS 127         // S-1
#define NROW 4064        // B*NPOS
#define LD1T 4064

typedef _Float16 h2f __attribute__((ext_vector_type(2)));

__device__ __forceinline__ float dot2f(UINT w, UINT h, float acc){
#if __has_builtin(__builtin_amdgcn_fdot2)
    return __builtin_amdgcn_fdot2(__builtin_bit_cast(h2f, w), __builtin_bit_cast(h2f, h), acc, false);
#else
    h2f a = __builtin_bit_cast(h2f, w); h2f b = __builtin_bit_cast(h2f, h);
    return acc + (float)a.x * (float)b.x + (float)a.y * (float)b.y;
#endif
}

__device__ __forceinline__ float sigm(float x){ return 1.f / (1.f + __expf(-x)); }
__device__ __forceinline__ float tanh_f(float x){ float e = __expf(2.f * x); return (e - 1.f) / (e + 1.f); }

// ---------- 1) Whh (3,2,1600,400) f32 -> f16 k-pair-packed, gate-interleaved ----------
// dst: uint4 per (ld, k2, j): { wi, wf, wg, wo } where each UINT = f16 pair (k=2*k2, 2*k2+1)
// layout index: [ld][k2][j]  (ld = layer*2+dir, k2 in 0..199, j in 0..399)
__global__ __launch_bounds__(256) void k_convert_whh(const float* __restrict__ whh, UINT* __restrict__ wpk){
    int idx = blockIdx.x * 256 + threadIdx.x;      // 0 .. 479,999
    if (idx >= 480000) return;
    int ld_i = idx / 80000;                        // layer*2+dir
    int rem  = idx % 80000;
    int k2 = rem / 400;
    int j  = rem % 400;
    const float* srcb = whh + (size_t)ld_i * G4 * HID + 2 * k2;
    UINT p[4];
    #pragma unroll
    for (int g = 0; g < 4; g++){
        const float* src = srcb + (size_t)(g * HID + j) * HID;
        _Float16 w0 = (_Float16)src[0];
        _Float16 w1 = (_Float16)src[1];
        p[g] = (UINT)__builtin_bit_cast(USHORT, w0) | ((UINT)__builtin_bit_cast(USHORT, w1) << 16);
    }
    uint4 v; v.x = p[0]; v.y = p[1]; v.z = p[2]; v.w = p[3];
    ((uint4*)wpk)[(size_t)ld_i * 80000 + (size_t)k2 * 400 + j] = v;
}

// ---------- 2) embedding concat -> x (4096 x 200) fp32 ----------
__global__ __launch_bounds__(64) void k_embed(const int* __restrict__ words, const int* __restrict__ tags,
                                              const float* __restrict__ wemb, const float* __restrict__ temb,
                                              float* __restrict__ xA){
    int tok = blockIdx.x;
    int w = words[tok], tg = tags[tok];
    float* dst = xA + (size_t)tok * 200;
    for (int i = threadIdx.x; i < 100; i += 64){
        dst[i]       = wemb[(size_t)w * 100 + i];
        dst[100 + i] = temb[(size_t)tg * 100 + i];
    }
}

// ---------- 3) input projection GEMM: Zh[dir][tok][o] = f16( bias + X @ Wih[dir].T ) ----------
__global__ __launch_bounds__(256) void k_gemm_ih(const float* __restrict__ X, int ldX, int K,
                                                 const float* __restrict__ Wih, const float* __restrict__ bias,
                                                 _Float16* __restrict__ Zh){
    int dir = blockIdx.z;
    int o0 = blockIdx.x * 64, tok0 = blockIdx.y * 64;
    const float* W  = Wih + (size_t)dir * G4 * K;
    const float* bb = bias + dir * G4;
    _Float16* Zd = Zh + (size_t)dir * TOKENS * G4;
    __shared__ float Xs[16][68];
    __shared__ float Ws[16][68];
    int tid = threadIdx.x;
    int tx = tid & 15, ty = tid >> 4;
    float acc[4][4];
    #pragma unroll
    for (int j = 0; j < 4; j++){
        float bv = bb[o0 + tx * 4 + j];
        #pragma unroll
        for (int i = 0; i < 4; i++) acc[i][j] = bv;
    }
    int lr = tid >> 2;          // 0..63
    int lc = (tid & 3) * 4;     // 0,4,8,12
    for (int k0 = 0; k0 < K; k0 += 16){
        float4 xv = {0.f,0.f,0.f,0.f};
        float4 wv = {0.f,0.f,0.f,0.f};
        if (k0 + lc < K){   // K % 4 == 0 -> quad fully in or out (K=200: tail at k0=192)
            xv = *(const float4*)(X + (size_t)(tok0 + lr) * ldX + k0 + lc);
            wv = *(const float4*)(W + (size_t)(o0 + lr) * K + k0 + lc);
        }
        __syncthreads();
        Xs[lc+0][lr] = xv.x; Xs[lc+1][lr] = xv.y; Xs[lc+2][lr] = xv.z; Xs[lc+3][lr] = xv.w;
        Ws[lc+0][lr] = wv.x; Ws[lc+1][lr] = wv.y; Ws[lc+2][lr] = wv.z; Ws[lc+3][lr] = wv.w;
        __syncthreads();
        #pragma unroll
        for (int kk = 0; kk < 16; kk++){
            float4 a = *(const float4*)&Xs[kk][ty * 4];
            float4 w = *(const float4*)&Ws[kk][tx * 4];
            float av[4] = {a.x, a.y, a.z, a.w};
            float wv2[4] = {w.x, w.y, w.z, w.w};
            #pragma unroll
            for (int i = 0; i < 4; i++)
                #pragma unroll
                for (int j = 0; j < 4; j++)
                    acc[i][j] += av[i] * wv2[j];
        }
    }
    #pragma unroll
    for (int i = 0; i < 4; i++){
        _Float16* zr = Zd + (size_t)(tok0 + ty * 4 + i) * G4 + o0 + tx * 4;
        #pragma unroll
        for (int j = 0; j < 4; j++) zr[j] = (_Float16)acc[i][j];
    }
}

// ---------- 4) LSTM recurrence: one block per (batch, dir) chain ----------
// weights: uint4 per (k2, j) = 4 gates x f16-pair; one dwordx4 load per k2 per thread
__global__ __launch_bounds__(512) void k_lstm(const _Float16* __restrict__ Zh, const UINT* __restrict__ wpk,
                                              float* __restrict__ Xout, int layer){
    int bi = blockIdx.x >> 1, dir = blockIdx.x & 1;
    const uint4* wp4 = (const uint4*)wpk + (size_t)(layer * 2 + dir) * 80000;
    const _Float16* Zd = Zh + (size_t)dir * TOKENS * G4 + (size_t)bi * SEQ * G4;
    float* Xo = Xout + (size_t)bi * SEQ * 800 + dir * HID;
    __shared__ __align__(16) _Float16 hsh[HID];
    UINT* hu = (UINT*)hsh;
    int tid = threadIdx.x;
    if (tid < 200) hu[tid] = 0u;
    float c = 0.f;
    int j = tid;
    __syncthreads();
    for (int s = 0; s < SEQ; s++){
        int t = dir ? (SEQ - 1 - s) : s;
        const _Float16* zr = Zd + (size_t)t * G4;
        float hval = 0.f;
        if (j < HID){
            float ai = (float)zr[j], af = (float)zr[HID + j];
            float ag = (float)zr[2*HID + j], ao = (float)zr[3*HID + j];
            const uint4* w0 = wp4 + j;
            #pragma unroll 4
            for (int k2 = 0; k2 < 200; k2++){
                UINT hp = hu[k2];
                uint4 w = w0[(size_t)k2 * 400];
                ai = dot2f(w.x, hp, ai);
                af = dot2f(w.y, hp, af);
                ag = dot2f(w.z, hp, ag);
                ao = dot2f(w.w, hp, ao);
            }
            float ig = sigm(ai), fg = sigm(af), gg = tanh_f(ag), og = sigm(ao);
            c = fg * c + ig * gg;
            hval = og * tanh_f(c);
            Xo[(size_t)t * 800 + j] = hval;
        }
        __syncthreads();
        if (j < HID) hsh[j] = (_Float16)hval;
        __syncthreads();
    }
}

// ---------- 5) MLPs -> transposed l1T/r1T [feature][row], row = b*127+x, ones at feature 100 ----------
__global__ __launch_bounds__(256) void k_mlp(const float* __restrict__ X,
                                             const float* __restrict__ Wl, const float* __restrict__ bl,
                                             const float* __restrict__ Wr, const float* __restrict__ br,
                                             float* __restrict__ l1T, float* __restrict__ r1T){
    int r = blockIdx.x;            // 0..4063
    int b = r / NPOS, x = r % NPOS;
    __shared__ float feat[800];
    const float* xrow = X + (size_t)(b * SEQ + x) * 800;
    int tid = threadIdx.x;
    // feat = [fwd(token x) 0..399 | bwd(token x+1) 400..799]
    for (int k = tid; k < 800; k += 256) feat[k] = (k < 400) ? xrow[k] : xrow[800 + k];
    __syncthreads();
    if (tid < 200){
        int isl = (tid < 100);
        int m = isl ? tid : tid - 100;
        const float* W = (isl ? Wl : Wr) + (size_t)m * 800;
        float acc = (isl ? bl : br)[m];
        for (int k = 0; k < 800; k += 4){
            float4 w4 = *(const float4*)(W + k);
            acc += w4.x * feat[k]   + w4.y * feat[k+1]
                 + w4.z * feat[k+2] + w4.w * feat[k+3];
        }
        float v = acc > 0.f ? acc : 0.1f * acc;
        (isl ? l1T : r1T)[(size_t)m * LD1T + r] = v;
    } else if (tid == 200){ l1T[(size_t)100 * LD1T + r] = 1.0f; }
    else if (tid == 201){ r1T[(size_t)100 * LD1T + r] = 1.0f; }
}

// ---------- 6) biaffine: block per (o, b); V = W_o * R1^T then S = L1 * V, all in LDS ----------
// dyn LDS: Wl 101*104 f32 | Rt 101*128 f32 | Vt 101*128 f32  = 145,440 B (Lt reuses Wl+Rt)
__global__ __launch_bounds__(256) void k_biaffine(const float* __restrict__ l1T, const float* __restrict__ r1T,
                                                  const float* __restrict__ BW, float* __restrict__ out){
    int o = blockIdx.x, b = blockIdx.y;
    extern __shared__ float sm[];
    float* Wl = sm;                  // 101*104
    float* Rt = sm + 101 * 104;      // 101*128
    float* Vt = Rt + 101 * 128;      // 101*128
    float* Lt = sm;                  // reuse after stage A
    int tid = threadIdx.x;
    const float* wo = BW + (size_t)o * 10201;
    for (int idx = tid; idx < 10201; idx += 256){
        int i = idx / 101, jj = idx % 101;
        Wl[i * 104 + jj] = wo[idx];
    }
    const float* rb = r1T + b * NPOS;
    for (int idx = tid; idx < 101 * 128; idx += 256){
        int jj = idx >> 7, y = idx & 127;
        Rt[idx] = (y < NPOS) ? rb[(size_t)jj * LD1T + y] : 0.f;
    }
    __syncthreads();
    {   // stage A: Vt[i][y] = sum_j Wl[i][j] * Rt[j][y]
        int ty = tid & 31, ti = tid >> 5;
        for (int i = ti; i < 101; i += 8){
            float a0 = 0.f, a1 = 0.f, a2 = 0.f, a3 = 0.f;
            const float* wrow = Wl + i * 104;
            #pragma unroll 2
            for (int jj = 0; jj < 101; jj++){
                float w = wrow[jj];
                float4 r4 = *(const float4*)(Rt + jj * 128 + ty * 4);
                a0 += w * r4.x; a1 += w * r4.y; a2 += w * r4.z; a3 += w * r4.w;
            }
            float4 v; v.x = a0; v.y = a1; v.z = a2; v.w = a3;
            *(float4*)(Vt + i * 128 + ty * 4) = v;
        }
    }
    __syncthreads();
    const float* lb = l1T + b * NPOS;
    for (int idx = tid; idx < 101 * 128; idx += 256){
        int ii = idx >> 7, x = idx & 127;
        Lt[idx] = (x < NPOS) ? lb[(size_t)ii * LD1T + x] : 0.f;
    }
    __syncthreads();
    {   // stage B: S[x][y] = sum_i Lt[i][x] * Vt[i][y]
        int tx = tid & 31, ty8 = tid >> 5;
        float* ob = out + (size_t)b * NPOS * NPOS * 128 + o;
        for (int yp = 0; yp < 4; yp++){
            int y0 = (ty8 + 8 * yp) * 4;
            float accm[4][4] = {};
            for (int i = 0; i < 101; i++){
                float4 l4 = *(const float4*)(Lt + i * 128 + tx * 4);
                float4 v4 = *(const float4*)(Vt + i * 128 + y0);
                float lv[4] = {l4.x, l4.y, l4.z, l4.w};
                float vv[4] = {v4.x, v4.y, v4.z, v4.w};
                #pragma unroll
                for (int xx = 0; xx < 4; xx++)
                    #pragma unroll
                    for (int yy = 0; yy < 4; yy++)
                        accm[xx][yy] += lv[xx] * vv[yy];
            }
            #pragma unroll
            for (int xx = 0; xx < 4; xx++){
                int x = tx * 4 + xx;
                if (x >= NPOS) continue;
                #pragma unroll
                for (int yy = 0; yy < 4; yy++){
                    int y = y0 + yy;
                    if (y >= NPOS) continue;
                    ob[((size_t)x * NPOS + y) * 128] = accm[xx][yy];
                }
            }
        }
    }
}

extern "C" void kernel_launch(void* const* d_in, const int* in_sizes, int n_in,
                              void* d_out, int out_size, void* d_ws, size_t ws_size,
                              hipStream_t stream) {
    const int* words = (const int*)d_in[0];
    const int* tags  = (const int*)d_in[1];
    const float* wemb = (const float*)d_in[2];
    const float* temb = (const float*)d_in[3];
    const float* wih[3] = {(const float*)d_in[4], (const float*)d_in[5], (const float*)d_in[6]};
    const float* whh  = (const float*)d_in[7];
    const float* bias = (const float*)d_in[8];
    const float* mlW = (const float*)d_in[9];
    const float* mlb = (const float*)d_in[10];
    const float* mrW = (const float*)d_in[11];
    const float* mrb = (const float*)d_in[12];
    const float* bw  = (const float*)d_in[13];
    float* out = (float*)d_out;

    // workspace layout (bytes): x f32 (13,107,200) | Zh f16 (26,214,400) | wpk u32 (7,680,000)
    // l1T/r1T alias the Zh region after the last LSTM layer.
    char* base = (char*)d_ws;
    float*     x   = (float*)base;
    _Float16*  Zh  = (_Float16*)(base + 13107200);
    UINT*      wpk = (UINT*)(base + 13107200 + 26214400);
    float*     l1T = (float*)Zh;
    float*     r1T = l1T + (size_t)104 * LD1T;

    k_convert_whh<<<1875, 256, 0, stream>>>(whh, wpk);
    k_embed<<<TOKENS, 64, 0, stream>>>(words, tags, wemb, temb, x);

    for (int l = 0; l < 3; l++){
        int K = l ? 800 : 200;
        k_gemm_ih<<<dim3(25, 64, 2), 256, 0, stream>>>(x, K, K, wih[l], bias + l * 2 * G4, Zh);
        k_lstm<<<64, 512, 0, stream>>>(Zh, wpk, x, l);   // reads only Zh, overwrites x in place
    }
    k_mlp<<<NROW, 256, 0, stream>>>(x, mlW, mlb, mrW, mrb, l1T, r1T);

    (void)hipFuncSetAttribute((const void*)k_biaffine, hipFuncAttributeMaxDynamicSharedMemorySize, 145440);
    k_biaffine<<<dim3(128, 32), 256, 145440, stream>>>(l1T, r1T, bw, out);
}

// Round 3
// 7001.022 us; speedup vs baseline: 1.0215x; 1.0215x over previous
//
#include <hip/hip_runtime.h>
#include <cstdint>
#include <cstddef>

typedef unsigned int UINT;
typedef unsigned short USHORT;

// ---------- constants ----------
// B=32 S=128 V=32000 NT=64 NE=100 H=400 NL=128 NM=100
#define TOKENS 4096      // B*S
#define HID 400
#define G4 1600          // 4*H
#define SEQ 128
#define NB 32
#define NPOS 127         // S-1
#define NROW 4064        // B*NPOS
#define LD1T 4064
#define CHUNK_B 4        // batches per biaffine/transpose chunk

typedef _Float16 h2f __attribute__((ext_vector_type(2)));

__device__ __forceinline__ float dot2f(UINT w, UINT h, float acc){
#if __has_builtin(__builtin_amdgcn_fdot2)
    return __builtin_amdgcn_fdot2(__builtin_bit_cast(h2f, w), __builtin_bit_cast(h2f, h), acc, false);
#else
    h2f a = __builtin_bit_cast(h2f, w); h2f b = __builtin_bit_cast(h2f, h);
    return acc + (float)a.x * (float)b.x + (float)a.y * (float)b.y;
#endif
}

__device__ __forceinline__ float sigm(float x){ return 1.f / (1.f + __expf(-x)); }
__device__ __forceinline__ float tanh_f(float x){ float e = __expf(2.f * x); return (e - 1.f) / (e + 1.f); }

// ---------- 1) Whh (3,2,1600,400) f32 -> f16 k-pair-packed, gate-interleaved ----------
__global__ __launch_bounds__(256) void k_convert_whh(const float* __restrict__ whh, UINT* __restrict__ wpk){
    int idx = blockIdx.x * 256 + threadIdx.x;      // 0 .. 479,999
    if (idx >= 480000) return;
    int ld_i = idx / 80000;                        // layer*2+dir
    int rem  = idx % 80000;
    int k2 = rem / 400;
    int j  = rem % 400;
    const float* srcb = whh + (size_t)ld_i * G4 * HID + 2 * k2;
    UINT p[4];
    #pragma unroll
    for (int g = 0; g < 4; g++){
        const float* src = srcb + (size_t)(g * HID + j) * HID;
        _Float16 w0 = (_Float16)src[0];
        _Float16 w1 = (_Float16)src[1];
        p[g] = (UINT)__builtin_bit_cast(USHORT, w0) | ((UINT)__builtin_bit_cast(USHORT, w1) << 16);
    }
    uint4 v; v.x = p[0]; v.y = p[1]; v.z = p[2]; v.w = p[3];
    ((uint4*)wpk)[(size_t)ld_i * 80000 + (size_t)k2 * 400 + j] = v;
}

// ---------- 2) embedding concat -> x (4096 x 200) fp32 ----------
__global__ __launch_bounds__(64) void k_embed(const int* __restrict__ words, const int* __restrict__ tags,
                                              const float* __restrict__ wemb, const float* __restrict__ temb,
                                              float* __restrict__ xA){
    int tok = blockIdx.x;
    int w = words[tok], tg = tags[tok];
    float* dst = xA + (size_t)tok * 200;
    for (int i = threadIdx.x; i < 100; i += 64){
        dst[i]       = wemb[(size_t)w * 100 + i];
        dst[100 + i] = temb[(size_t)tg * 100 + i];
    }
}

// ---------- 3) input projection GEMM ----------
__global__ __launch_bounds__(256) void k_gemm_ih(const float* __restrict__ X, int ldX, int K,
                                                 const float* __restrict__ Wih, const float* __restrict__ bias,
                                                 _Float16* __restrict__ Zh){
    int dir = blockIdx.z;
    int o0 = blockIdx.x * 64, tok0 = blockIdx.y * 64;
    const float* W  = Wih + (size_t)dir * G4 * K;
    const float* bb = bias + dir * G4;
    _Float16* Zd = Zh + (size_t)dir * TOKENS * G4;
    __shared__ float Xs[16][68];
    __shared__ float Ws[16][68];
    int tid = threadIdx.x;
    int tx = tid & 15, ty = tid >> 4;
    float acc[4][4];
    #pragma unroll
    for (int j = 0; j < 4; j++){
        float bv = bb[o0 + tx * 4 + j];
        #pragma unroll
        for (int i = 0; i < 4; i++) acc[i][j] = bv;
    }
    int lr = tid >> 2;          // 0..63
    int lc = (tid & 3) * 4;     // 0,4,8,12
    for (int k0 = 0; k0 < K; k0 += 16){
        float4 xv = {0.f,0.f,0.f,0.f};
        float4 wv = {0.f,0.f,0.f,0.f};
        if (k0 + lc < K){
            xv = *(const float4*)(X + (size_t)(tok0 + lr) * ldX + k0 + lc);
            wv = *(const float4*)(W + (size_t)(o0 + lr) * K + k0 + lc);
        }
        __syncthreads();
        Xs[lc+0][lr] = xv.x; Xs[lc+1][lr] = xv.y; Xs[lc+2][lr] = xv.z; Xs[lc+3][lr] = xv.w;
        Ws[lc+0][lr] = wv.x; Ws[lc+1][lr] = wv.y; Ws[lc+2][lr] = wv.z; Ws[lc+3][lr] = wv.w;
        __syncthreads();
        #pragma unroll
        for (int kk = 0; kk < 16; kk++){
            float4 a = *(const float4*)&Xs[kk][ty * 4];
            float4 w = *(const float4*)&Ws[kk][tx * 4];
            float av[4] = {a.x, a.y, a.z, a.w};
            float wv2[4] = {w.x, w.y, w.z, w.w};
            #pragma unroll
            for (int i = 0; i < 4; i++)
                #pragma unroll
                for (int j = 0; j < 4; j++)
                    acc[i][j] += av[i] * wv2[j];
        }
    }
    #pragma unroll
    for (int i = 0; i < 4; i++){
        _Float16* zr = Zd + (size_t)(tok0 + ty * 4 + i) * G4 + o0 + tx * 4;
        #pragma unroll
        for (int j = 0; j < 4; j++) zr[j] = (_Float16)acc[i][j];
    }
}

// ---------- 4) LSTM recurrence ----------
__global__ __launch_bounds__(512) void k_lstm(const _Float16* __restrict__ Zh, const UINT* __restrict__ wpk,
                                              float* __restrict__ Xout, int layer){
    int bi = blockIdx.x >> 1, dir = blockIdx.x & 1;
    const uint4* wp4 = (const uint4*)wpk + (size_t)(layer * 2 + dir) * 80000;
    const _Float16* Zd = Zh + (size_t)dir * TOKENS * G4 + (size_t)bi * SEQ * G4;
    float* Xo = Xout + (size_t)bi * SEQ * 800 + dir * HID;
    __shared__ __align__(16) _Float16 hsh[HID];
    UINT* hu = (UINT*)hsh;
    int tid = threadIdx.x;
    if (tid < 200) hu[tid] = 0u;
    float c = 0.f;
    int j = tid;
    __syncthreads();
    for (int s = 0; s < SEQ; s++){
        int t = dir ? (SEQ - 1 - s) : s;
        const _Float16* zr = Zd + (size_t)t * G4;
        float hval = 0.f;
        if (j < HID){
            float ai = (float)zr[j], af = (float)zr[HID + j];
            float ag = (float)zr[2*HID + j], ao = (float)zr[3*HID + j];
            const uint4* w0 = wp4 + j;
            #pragma unroll 4
            for (int k2 = 0; k2 < 200; k2++){
                UINT hp = hu[k2];
                uint4 w = w0[(size_t)k2 * 400];
                ai = dot2f(w.x, hp, ai);
                af = dot2f(w.y, hp, af);
                ag = dot2f(w.z, hp, ag);
                ao = dot2f(w.w, hp, ao);
            }
            float ig = sigm(ai), fg = sigm(af), gg = tanh_f(ag), og = sigm(ao);
            c = fg * c + ig * gg;
            hval = og * tanh_f(c);
            Xo[(size_t)t * 800 + j] = hval;
        }
        __syncthreads();
        if (j < HID) hsh[j] = (_Float16)hval;
        __syncthreads();
    }
}

// ---------- 5) MLPs -> transposed l1T/r1T [feature][row] ----------
__global__ __launch_bounds__(256) void k_mlp(const float* __restrict__ X,
                                             const float* __restrict__ Wl, const float* __restrict__ bl,
                                             const float* __restrict__ Wr, const float* __restrict__ br,
                                             float* __restrict__ l1T, float* __restrict__ r1T){
    int r = blockIdx.x;            // 0..4063
    int b = r / NPOS, x = r % NPOS;
    __shared__ float feat[800];
    const float* xrow = X + (size_t)(b * SEQ + x) * 800;
    int tid = threadIdx.x;
    for (int k = tid; k < 800; k += 256) feat[k] = (k < 400) ? xrow[k] : xrow[800 + k];
    __syncthreads();
    if (tid < 200){
        int isl = (tid < 100);
        int m = isl ? tid : tid - 100;
        const float* W = (isl ? Wl : Wr) + (size_t)m * 800;
        float acc = (isl ? bl : br)[m];
        for (int k = 0; k < 800; k += 4){
            float4 w4 = *(const float4*)(W + k);
            acc += w4.x * feat[k]   + w4.y * feat[k+1]
                 + w4.z * feat[k+2] + w4.w * feat[k+3];
        }
        float v = acc > 0.f ? acc : 0.1f * acc;
        (isl ? l1T : r1T)[(size_t)m * LD1T + r] = v;
    } else if (tid == 200){ l1T[(size_t)100 * LD1T + r] = 1.0f; }
    else if (tid == 201){ r1T[(size_t)100 * LD1T + r] = 1.0f; }
}

// ---------- 6a) biaffine -> T[bb][o][x][ypad128], coalesced stores ----------
// dyn LDS: Wl 101*104 | Rt 101*128 | Vt 101*128 = 145,440 B (Lt reuses Wl+Rt)
__global__ __launch_bounds__(256) void k_biaffineT(const float* __restrict__ l1T, const float* __restrict__ r1T,
                                                   const float* __restrict__ BW, float* __restrict__ T, int b0){
    int o = blockIdx.x, bb = blockIdx.y, b = b0 + bb;
    extern __shared__ float sm[];
    float* Wl = sm;                  // 101*104
    float* Rt = sm + 101 * 104;      // 101*128
    float* Vt = Rt + 101 * 128;      // 101*128
    float* Lt = sm;                  // reuse after stage A
    int tid = threadIdx.x;
    const float* wo = BW + (size_t)o * 10201;
    for (int idx = tid; idx < 10201; idx += 256){
        int i = idx / 101, jj = idx % 101;
        Wl[i * 104 + jj] = wo[idx];
    }
    const float* rb = r1T + b * NPOS;
    for (int idx = tid; idx < 101 * 128; idx += 256){
        int jj = idx >> 7, y = idx & 127;
        Rt[idx] = (y < NPOS) ? rb[(size_t)jj * LD1T + y] : 0.f;
    }
    __syncthreads();
    {   // stage A: Vt[i][y] = sum_j Wl[i][j] * Rt[j][y]
        int ty = tid & 31, ti = tid >> 5;
        for (int i = ti; i < 101; i += 8){
            float a0 = 0.f, a1 = 0.f, a2 = 0.f, a3 = 0.f;
            const float* wrow = Wl + i * 104;
            #pragma unroll 2
            for (int jj = 0; jj < 101; jj++){
                float w = wrow[jj];
                float4 r4 = *(const float4*)(Rt + jj * 128 + ty * 4);
                a0 += w * r4.x; a1 += w * r4.y; a2 += w * r4.z; a3 += w * r4.w;
            }
            float4 v; v.x = a0; v.y = a1; v.z = a2; v.w = a3;
            *(float4*)(Vt + i * 128 + ty * 4) = v;
        }
    }
    __syncthreads();
    const float* lb = l1T + b * NPOS;
    for (int idx = tid; idx < 101 * 128; idx += 256){
        int ii = idx >> 7, x = idx & 127;
        Lt[idx] = (x < NPOS) ? lb[(size_t)ii * LD1T + x] : 0.f;
    }
    __syncthreads();
    {   // stage B: S[x][y] = sum_i Lt[i][x] * Vt[i][y]; lanes vary y -> coalesced T stores
        int ty = tid & 31;          // y-quad: y = ty*4 + yy (0..127, incl pad col 127)
        int tx8 = tid >> 5;         // x base
        float* tb = T + (size_t)(bb * 128 + o) * 127 * 128;
        for (int xp = 0; xp < 4; xp++){
            int x0 = (tx8 + 8 * xp) * 4;
            float accm[4][4] = {};   // [xx][yy]
            for (int i = 0; i < 101; i++){
                float4 l4 = *(const float4*)(Lt + i * 128 + x0);      // broadcast in lane group
                float4 v4 = *(const float4*)(Vt + i * 128 + ty * 4);  // per-lane
                float lv[4] = {l4.x, l4.y, l4.z, l4.w};
                float vv[4] = {v4.x, v4.y, v4.z, v4.w};
                #pragma unroll
                for (int xx = 0; xx < 4; xx++)
                    #pragma unroll
                    for (int yy = 0; yy < 4; yy++)
                        accm[xx][yy] += lv[xx] * vv[yy];
            }
            #pragma unroll
            for (int xx = 0; xx < 4; xx++){
                int x = x0 + xx;
                if (x >= NPOS) continue;
                float4 w; w.x = accm[xx][0]; w.y = accm[xx][1]; w.z = accm[xx][2]; w.w = accm[xx][3];
                *(float4*)(tb + (size_t)x * 128 + ty * 4) = w;   // 32 lanes -> 512B contiguous
            }
        }
    }
}

// ---------- 6b) transpose T[bb][o][x][ypad] -> out[b][x][y][o], coalesced both sides ----------
// dyn LDS: ts[128][129] f32 = 66,048 B
__global__ __launch_bounds__(256) void k_transpose(const float* __restrict__ T, float* __restrict__ out, int b0){
    int x = blockIdx.x, bb = blockIdx.y, b = b0 + bb;
    extern __shared__ float ts[];    // [o][129]
    int tid = threadIdx.x;
    // load: rows o, contiguous y (float4)
    for (int idx = tid; idx < 128 * 32; idx += 256){
        int o = idx >> 5, y4 = idx & 31;
        float4 v = *(const float4*)(T + ((size_t)(bb * 128 + o) * 127 + x) * 128 + y4 * 4);
        float* d = ts + o * 129 + y4 * 4;
        d[0] = v.x; d[1] = v.y; d[2] = v.z; d[3] = v.w;
    }
    __syncthreads();
    // store: rows y, contiguous o (float4); lanes cover o 0..127 -> 512B runs
    float* ob = out + ((size_t)(b * NPOS + x)) * NPOS * 128;
    for (int idx = tid; idx < NPOS * 32; idx += 256){
        int y = idx >> 5, o4 = idx & 31;
        float4 w;
        w.x = ts[(o4 * 4 + 0) * 129 + y];
        w.y = ts[(o4 * 4 + 1) * 129 + y];
        w.z = ts[(o4 * 4 + 2) * 129 + y];
        w.w = ts[(o4 * 4 + 3) * 129 + y];
        *(float4*)(ob + (size_t)y * 128 + o4 * 4) = w;
    }
}

extern "C" void kernel_launch(void* const* d_in, const int* in_sizes, int n_in,
                              void* d_out, int out_size, void* d_ws, size_t ws_size,
                              hipStream_t stream) {
    const int* words = (const int*)d_in[0];
    const int* tags  = (const int*)d_in[1];
    const float* wemb = (const float*)d_in[2];
    const float* temb = (const float*)d_in[3];
    const float* wih[3] = {(const float*)d_in[4], (const float*)d_in[5], (const float*)d_in[6]};
    const float* whh  = (const float*)d_in[7];
    const float* bias = (const float*)d_in[8];
    const float* mlW = (const float*)d_in[9];
    const float* mlb = (const float*)d_in[10];
    const float* mrW = (const float*)d_in[11];
    const float* mrb = (const float*)d_in[12];
    const float* bw  = (const float*)d_in[13];
    float* out = (float*)d_out;

    // workspace layout (bytes):
    //   [0 .. 13,107,200)            x f32 (reused as T after k_mlp)
    //   [13,107,200 .. 39,321,600)   Zh f16 (T overlaps this region too during biaffine)
    //   [39,321,600 .. 47,001,600)   wpk u32 during LSTM; l1T/r1T live here after last LSTM
    char* base = (char*)d_ws;
    float*     x   = (float*)base;
    _Float16*  Zh  = (_Float16*)(base + 13107200);
    UINT*      wpk = (UINT*)(base + 13107200 + 26214400);
    float*     l1T = (float*)(base + 39321600);              // in dead wpk region (3.38 MB used of 7.68)
    float*     r1T = l1T + (size_t)104 * LD1T;
    float*     T   = (float*)base;                           // 33.3 MB chunk, x+Zh dead by then

    k_convert_whh<<<1875, 256, 0, stream>>>(whh, wpk);
    k_embed<<<TOKENS, 64, 0, stream>>>(words, tags, wemb, temb, x);

    for (int l = 0; l < 3; l++){
        int K = l ? 800 : 200;
        k_gemm_ih<<<dim3(25, 64, 2), 256, 0, stream>>>(x, K, K, wih[l], bias + l * 2 * G4, Zh);
        k_lstm<<<64, 512, 0, stream>>>(Zh, wpk, x, l);
    }
    k_mlp<<<NROW, 256, 0, stream>>>(x, mlW, mlb, mrW, mrb, l1T, r1T);

    (void)hipFuncSetAttribute((const void*)k_biaffineT, hipFuncAttributeMaxDynamicSharedMemorySize, 145440);
    (void)hipFuncSetAttribute((const void*)k_transpose, hipFuncAttributeMaxDynamicSharedMemorySize, 66048);
    for (int c = 0; c < NB / CHUNK_B; c++){
        k_biaffineT<<<dim3(128, CHUNK_B), 256, 145440, stream>>>(l1T, r1T, bw, T, c * CHUNK_B);
        k_transpose<<<dim3(NPOS, CHUNK_B), 256, 66048, stream>>>(T, out, c * CHUNK_B);
    }
}